// Round 2
// 228.429 us; speedup vs baseline: 1.1023x; 1.1023x over previous
//
#include <hip/hip_runtime.h>
#include <cstdint>
#include <cstddef>

// Problem constants (N=2, C=128, Ce=64, H=W=96)
#define HW_ 9216
#define CC 128
#define NQT 144      // HW/64 Q-tiles
#define LOG2E 1.44269504088896f
#define RESCALE_THR 8.0f

typedef short bf16x8 __attribute__((ext_vector_type(8)));
typedef unsigned short u16x4 __attribute__((ext_vector_type(4)));
typedef float f32x4 __attribute__((ext_vector_type(4)));

__device__ __forceinline__ unsigned short f2bf(float f) {
    unsigned int u = __builtin_bit_cast(unsigned int, f);
    u += 0x7FFFu + ((u >> 16) & 1u);   // RNE
    return (unsigned short)(u >> 16);
}

__device__ __forceinline__ float fast_exp2(float x) {
#if __has_builtin(__builtin_amdgcn_exp2f)
    return __builtin_amdgcn_exp2f(x);   // bare v_exp_f32
#else
    return exp2f(x);
#endif
}

__device__ __forceinline__ float max3f(float a, float b, float c) {
    float r;
    asm("v_max3_f32 %0, %1, %2, %3" : "=v"(r) : "v"(a), "v"(b), "v"(c));
    return r;
}

__device__ __forceinline__ unsigned int cvt_pk_bf16(float lo, float hi) {
    unsigned int r;
    asm("v_cvt_pk_bf16_f32 %0, %1, %2" : "=v"(r) : "v"(lo), "v"(hi));
    return r;
}

// ---------------------------------------------------------------------------
// Kernel 1: transpose weights into wt[c][o], o in [0,256): 0..63=w1, 64..127=w2,
// 128..255=wa.
// ---------------------------------------------------------------------------
__global__ __launch_bounds__(256) void prep_w(const float* __restrict__ w1,
                                              const float* __restrict__ w2,
                                              const float* __restrict__ wa,
                                              float* __restrict__ wt) {
    int idx = blockIdx.x * 256 + threadIdx.x;   // 32768 total
    int o = idx >> 7, c = idx & 127;
    float v;
    if (o < 64)       v = w1[o * 128 + c];
    else if (o < 128) v = w2[(o - 64) * 128 + c];
    else              v = wa[(o - 128) * 128 + c];
    wt[c * 256 + o] = v;
}

// ---------------------------------------------------------------------------
// Kernel 2: 1x1 conv + PReLU (fp32 accumulate), write bf16.
//   oset 0 -> Q[n][p][d] (pre-scaled by log2e; PReLU commutes with pos scale)
//   oset 1 -> K[n][p][d]
//   oset 2,3 -> Vt[n][c][p]
// ---------------------------------------------------------------------------
__global__ __launch_bounds__(256) void conv_kernel(
    const float* __restrict__ x, const float* __restrict__ wt,
    const float* __restrict__ b1, const float* __restrict__ a1,
    const float* __restrict__ b2, const float* __restrict__ a2,
    const float* __restrict__ ba, const float* __restrict__ aa,
    unsigned short* __restrict__ qb, unsigned short* __restrict__ kb,
    unsigned short* __restrict__ vtb) {
    const int ptile = blockIdx.x;   // 144
    const int oset  = blockIdx.y;   // 4
    const int n     = blockIdx.z;   // 2
    const int t = threadIdx.x;
    const int p = t & 63;
    const int og = __builtin_amdgcn_readfirstlane(t >> 6);
    const int p0 = ptile * 64;

    __shared__ float xs[128 * 64];
    for (int c = t >> 6; c < 128; c += 4)
        xs[c * 64 + p] = x[((size_t)n * CC + c) * HW_ + p0 + p];
    __syncthreads();

    const int obase = oset * 64 + og * 16;
    float acc[16];
#pragma unroll
    for (int i = 0; i < 16; i++) acc[i] = 0.f;

    for (int c = 0; c < 128; c++) {
        float xv = xs[c * 64 + p];
        const float* wr = wt + c * 256 + obase;   // uniform -> s_load
#pragma unroll
        for (int i = 0; i < 16; i++) acc[i] = fmaf(wr[i], xv, acc[i]);
    }

    const float* bias_p;
    const float* slope_p;
    if (oset == 0)      { bias_p = b1; slope_p = a1; }
    else if (oset == 1) { bias_p = b2; slope_p = a2; }
    else                { bias_p = ba; slope_p = aa; }
    const float slope = slope_p[0];

    unsigned short vals[16];
#pragma unroll
    for (int i = 0; i < 16; i++) {
        float bv = (oset < 2) ? bias_p[og * 16 + i] : bias_p[obase - 128 + i];
        float y = acc[i] + bv;
        y = (y >= 0.f) ? y : slope * y;
        if (oset == 0) y *= LOG2E;   // fold softmax's ln->log2 into Q
        vals[i] = f2bf(y);
    }

    if (oset < 2) {
        unsigned short* dst = (oset == 0 ? qb : kb) + ((size_t)n * HW_ + p0 + p) * 64 + og * 16;
        bf16x8 v0, v1;
#pragma unroll
        for (int i = 0; i < 8; i++) { v0[i] = (short)vals[i]; v1[i] = (short)vals[8 + i]; }
        *(bf16x8*)(dst)     = v0;
        *(bf16x8*)(dst + 8) = v1;
    } else {
        int c0 = obase - 128;
#pragma unroll
        for (int i = 0; i < 16; i++)
            vtb[((size_t)n * CC + c0 + i) * HW_ + p0 + p] = vals[i];
    }
}

// ---------------------------------------------------------------------------
// Kernel 3: flash attention, S^T formulation.
//   S^T = K·Q^T  (A=K, B=Q)  -> C/D: col = q = lane&15, row = j = quad*4+r
//   softmax: in-lane over 16 + 2 shfl_xor (quads); m scalar per lane
//   defer-max (THR=8, log2 domain): skip acc rescale unless max grows
//   l via ones-row MFMA: acc_l = mfma(av_one, P) accumulates row sums of P
//   P^T -> per-wave LDS [q][j] via cvt_pk_bf16 + 4 ds_write_b64, no barrier
//   O^T = V^T·P^T (A=V^T, B=P^T) -> col = q, row = c-local
// Block = 4 waves x 16 q-rows = 64 q. KV chunked over blockIdx.y.
// ---------------------------------------------------------------------------
__global__ __launch_bounds__(256, 4) void attn_kernel(
    const unsigned short* __restrict__ qb, const unsigned short* __restrict__ kb,
    const unsigned short* __restrict__ vtb,
    float* __restrict__ o_part, float* __restrict__ ml_part,
    int nch, int chunk_j) {
    const int qt    = blockIdx.x;   // 144
    const int chunk = blockIdx.y;   // nch
    const int n     = blockIdx.z;   // 2
    const int t = threadIdx.x;
    const int w = t >> 6;
    const int lane = t & 63;
    const int l15 = lane & 15;
    const int quad = lane >> 4;
    const int e7 = l15 & 7;

    __shared__ __align__(16) unsigned short k_lds[64 * 64];     // [j][d] swizzled
    __shared__ __align__(16) unsigned short v_lds[128 * 64];    // [c][j] swizzled
    __shared__ __align__(16) unsigned short p_lds[4 * 16 * 64]; // per-wave [q][j] swizzled

    // Q B-fragments: B[k=d][n=q]: lane holds q=l15, d = quad*8.. contiguous
    const int row_g = qt * 64 + w * 16 + l15;
    const bf16x8 bq0 = *(const bf16x8*)(qb + ((size_t)n * HW_ + row_g) * 64 + quad * 8);
    const bf16x8 bq1 = *(const bf16x8*)(qb + ((size_t)n * HW_ + row_g) * 64 + 32 + quad * 8);

    // ones-row A fragment: row c_local=0 (supplied by l15==0 lanes) = 1.0bf16
    bf16x8 av_one;
#pragma unroll
    for (int i = 0; i < 8; i++) av_one[i] = (l15 == 0) ? (short)0x3F80 : (short)0;

    f32x4 acc_o[8];
#pragma unroll
    for (int i = 0; i < 8; i++) acc_o[i] = (f32x4){0.f, 0.f, 0.f, 0.f};
    f32x4 acc_l = (f32x4){0.f, 0.f, 0.f, 0.f};   // row 0 (quad0,r0) = sum_j P[q][j]
    float m_s = -INFINITY;

    const int stg_row = t >> 3, stg_seg = t & 7;
    const int iters = chunk_j / 64;
    int j0 = chunk * chunk_j;

    // software pipeline: prefetch tile 0 into VGPRs
    bf16x8 kr0, kr1, vr0, vr1, vr2, vr3;
    {
        const unsigned short* kp = kb + ((size_t)n * HW_ + j0 + stg_row) * 64 + stg_seg * 8;
        kr0 = *(const bf16x8*)kp;
        kr1 = *(const bf16x8*)(kp + 32 * 64);
        const unsigned short* vp = vtb + ((size_t)n * CC + stg_row) * HW_ + j0 + stg_seg * 8;
        vr0 = *(const bf16x8*)vp;
        vr1 = *(const bf16x8*)(vp + (size_t)32 * HW_);
        vr2 = *(const bf16x8*)(vp + (size_t)64 * HW_);
        vr3 = *(const bf16x8*)(vp + (size_t)96 * HW_);
    }

    for (int it = 0; it < iters; ++it, j0 += 64) {
        __syncthreads();   // previous iteration's k/v_lds reads complete
        {
            int r0 = stg_row, r1 = stg_row + 32;
            *(bf16x8*)&k_lds[r0 * 64 + ((stg_seg ^ (r0 & 7)) * 8)] = kr0;
            *(bf16x8*)&k_lds[r1 * 64 + ((stg_seg ^ (r1 & 7)) * 8)] = kr1;
            *(bf16x8*)&v_lds[r0 * 64 + ((stg_seg ^ (r0 & 7)) * 8)] = vr0;
            *(bf16x8*)&v_lds[r1 * 64 + ((stg_seg ^ (r1 & 7)) * 8)] = vr1;
            int r2 = stg_row + 64, r3 = stg_row + 96;
            *(bf16x8*)&v_lds[r2 * 64 + ((stg_seg ^ (r2 & 7)) * 8)] = vr2;
            *(bf16x8*)&v_lds[r3 * 64 + ((stg_seg ^ (r3 & 7)) * 8)] = vr3;
        }
        __syncthreads();

        if (it + 1 < iters) {   // issue next tile's loads; overlap with compute
            const unsigned short* kp = kb + ((size_t)n * HW_ + j0 + 64 + stg_row) * 64 + stg_seg * 8;
            kr0 = *(const bf16x8*)kp;
            kr1 = *(const bf16x8*)(kp + 32 * 64);
            const unsigned short* vp = vtb + ((size_t)n * CC + stg_row) * HW_ + j0 + 64 + stg_seg * 8;
            vr0 = *(const bf16x8*)vp;
            vr1 = *(const bf16x8*)(vp + (size_t)32 * HW_);
            vr2 = *(const bf16x8*)(vp + (size_t)64 * HW_);
            vr3 = *(const bf16x8*)(vp + (size_t)96 * HW_);
        }

        // S^T = K Q^T: 4 tiles along j (16 each)
        f32x4 s[4];
#pragma unroll
        for (int ct = 0; ct < 4; ct++) {
            int jr = ct * 16 + l15;
            bf16x8 ak0 = *(const bf16x8*)&k_lds[jr * 64 + ((quad ^ e7) * 8)];
            bf16x8 ak1 = *(const bf16x8*)&k_lds[jr * 64 + (((4 + quad) ^ e7) * 8)];
            f32x4 a = (f32x4){0.f, 0.f, 0.f, 0.f};
            a = __builtin_amdgcn_mfma_f32_16x16x32_bf16(ak0, bq0, a, 0, 0, 0);
            a = __builtin_amdgcn_mfma_f32_16x16x32_bf16(ak1, bq1, a, 0, 0, 0);
            s[ct] = a;
        }

        // tile max: v_max3 tree over 16 in-lane values (all share q = l15)
        float smax = max3f(s[0][0], s[0][1], s[0][2]);
        smax = max3f(smax, s[0][3], s[1][0]);
        smax = max3f(smax, s[1][1], s[1][2]);
        smax = max3f(smax, s[1][3], s[2][0]);
        smax = max3f(smax, s[2][1], s[2][2]);
        smax = max3f(smax, s[2][3], s[3][0]);
        smax = max3f(smax, s[3][1], s[3][2]);
        smax = fmaxf(smax, s[3][3]);
        smax = fmaxf(smax, __shfl_xor(smax, 16));
        smax = fmaxf(smax, __shfl_xor(smax, 32));

        // defer-max: only rescale when the running max actually grows > THR.
        // P is then bounded by 2^THR = 256 (fine in bf16 / fp32 accum).
        if (__any(smax > m_s + RESCALE_THR)) {
            float mnew = fmaxf(m_s, smax);
            float alpha = fast_exp2(m_s - mnew);   // -inf first iter -> 0
            m_s = mnew;
#pragma unroll
            for (int i = 0; i < 8; i++) acc_o[i] *= alpha;   // v_pk_mul_f32
            acc_l *= alpha;
        }

        // P = exp2(S - m); l accumulated by ones-row MFMA below (no scalar sum)
        f32x4 m4 = (f32x4){m_s, m_s, m_s, m_s};
#pragma unroll
        for (int ct = 0; ct < 4; ct++) {
            f32x4 e = s[ct] - m4;   // v_pk_add_f32
            s[ct][0] = fast_exp2(e[0]);
            s[ct][1] = fast_exp2(e[1]);
            s[ct][2] = fast_exp2(e[2]);
            s[ct][3] = fast_exp2(e[3]);
        }

        // P^T -> per-wave LDS [q][j]: j = 16ct + 4quad + r, 4 contiguous -> b64
        // pack via v_cvt_pk_bf16_f32 (2 f32 -> 1 dword, RNE)
#pragma unroll
        for (int ct = 0; ct < 4; ct++) {
            unsigned int pk01 = cvt_pk_bf16(s[ct][0], s[ct][1]);
            unsigned int pk23 = cvt_pk_bf16(s[ct][2], s[ct][3]);
            int chunkid = 2 * ct + (quad >> 1);
            int off = l15 * 64 + ((chunkid ^ e7) * 8) + 4 * (quad & 1);
            uint2 pk;
            pk.x = pk01;
            pk.y = pk23;
            *(uint2*)&p_lds[w * 1024 + off] = pk;
        }
        // same-wave readback: compiler inserts lgkmcnt wait; no barrier needed
        const bf16x8 bp0 = *(const bf16x8*)&p_lds[w * 1024 + l15 * 64 + ((quad ^ e7) * 8)];
        const bf16x8 bp1 = *(const bf16x8*)&p_lds[w * 1024 + l15 * 64 + (((4 + quad) ^ e7) * 8)];

        // O^T += V^T P^T ; l += 1^T P^T (ones-row)
        __builtin_amdgcn_s_setprio(1);
        acc_l = __builtin_amdgcn_mfma_f32_16x16x32_bf16(av_one, bp0, acc_l, 0, 0, 0);
        acc_l = __builtin_amdgcn_mfma_f32_16x16x32_bf16(av_one, bp1, acc_l, 0, 0, 0);
#pragma unroll
        for (int ctv = 0; ctv < 8; ctv++) {
            int cr = ctv * 16 + l15;
            bf16x8 av0 = *(const bf16x8*)&v_lds[cr * 64 + ((quad ^ e7) * 8)];
            bf16x8 av1 = *(const bf16x8*)&v_lds[cr * 64 + (((4 + quad) ^ e7) * 8)];
            acc_o[ctv] = __builtin_amdgcn_mfma_f32_16x16x32_bf16(av0, bp0, acc_o[ctv], 0, 0, 0);
            acc_o[ctv] = __builtin_amdgcn_mfma_f32_16x16x32_bf16(av1, bp1, acc_o[ctv], 0, 0, 0);
        }
        __builtin_amdgcn_s_setprio(0);
    }

    // partials: O^T layout [c][q] — rows c = 16ctv+4quad+r, col q = w*16+l15
    const size_t cbase = ((size_t)(n * NQT + qt) * nch + chunk) * 128;
    const int qloc = w * 16 + l15;
#pragma unroll
    for (int ctv = 0; ctv < 8; ctv++)
#pragma unroll
        for (int r = 0; r < 4; r++) {
            int c = ctv * 16 + 4 * quad + r;
            o_part[(cbase + c) * 64 + qloc] = acc_o[ctv][r];
        }
    if (quad == 0) {   // m is quad-uniform per q; l lives in acc_l[0] row 0
        size_t mlb = ((size_t)(n * NQT + qt) * nch + chunk) * 128;
        ml_part[mlb + qloc]      = m_s;
        ml_part[mlb + 64 + qloc] = acc_l[0];
    }
}

// ---------------------------------------------------------------------------
// Kernel 4: combine nch partials, normalize, write out[n][c][p] fp32.
// ---------------------------------------------------------------------------
__global__ __launch_bounds__(256) void combine_kernel(
    const float* __restrict__ o_part, const float* __restrict__ ml,
    float* __restrict__ out, int nch) {
    int gid = blockIdx.x * 256 + threadIdx.x;
    int r = gid & 63;
    int rest = gid >> 6;
    int c = rest & 127;
    int nqt = rest >> 7;           // 0..287
    int n = nqt / NQT, qtp = nqt - n * NQT;

    float mv[4], lv[4];
    float ms = -INFINITY;
    for (int ch = 0; ch < nch; ch++) {
        size_t mlb = ((size_t)nqt * nch + ch) * 128;
        mv[ch] = ml[mlb + r];
        lv[ch] = ml[mlb + 64 + r];
        ms = fmaxf(ms, mv[ch]);
    }
    float num = 0.f, den = 0.f;
    for (int ch = 0; ch < nch; ch++) {
        float e = exp2f(mv[ch] - ms);
        num = fmaf(e, o_part[(((size_t)nqt * nch + ch) * 128 + c) * 64 + r], num);
        den = fmaf(e, lv[ch], den);
    }
    out[((size_t)n * CC + c) * HW_ + qtp * 64 + r] = num / den;
}

// ---------------------------------------------------------------------------
// Workspace layout (bytes):
//   wt 0 (131072) | qb 131072 (2359296) | kb 2490368 (2359296)
//   vtb 4849664 (4718592) | o_part 9568256 (nch*9437184) | ml after o_part
// nch=4 needs ~47.9 MB; falls back to nch=2 (28.7 MB, round-1-proven) if tight.
// ---------------------------------------------------------------------------
extern "C" void kernel_launch(void* const* d_in, const int* in_sizes, int n_in,
                              void* d_out, int out_size, void* d_ws, size_t ws_size,
                              hipStream_t stream) {
    const float* x  = (const float*)d_in[0];
    const float* w1 = (const float*)d_in[1];
    const float* b1 = (const float*)d_in[2];
    const float* a1 = (const float*)d_in[3];
    const float* w2 = (const float*)d_in[4];
    const float* b2 = (const float*)d_in[5];
    const float* a2 = (const float*)d_in[6];
    const float* wa = (const float*)d_in[7];
    const float* ba = (const float*)d_in[8];
    const float* aa = (const float*)d_in[9];
    float* out = (float*)d_out;

    const size_t need4 = 9568256 + 4ull * 9437184 + 4ull * 288 * 128 * 4;
    const int nch = (ws_size >= need4) ? 4 : 2;
    const int chunk_j = HW_ / nch;

    char* ws = (char*)d_ws;
    float*          wt     = (float*)(ws + 0);
    unsigned short* qb     = (unsigned short*)(ws + 131072);
    unsigned short* kb     = (unsigned short*)(ws + 2490368);
    unsigned short* vtb    = (unsigned short*)(ws + 4849664);
    float*          o_part = (float*)(ws + 9568256);
    float*          ml     = (float*)(ws + 9568256 + (size_t)nch * 9437184);

    hipLaunchKernelGGL(prep_w, dim3(128), dim3(256), 0, stream, w1, w2, wa, wt);
    hipLaunchKernelGGL(conv_kernel, dim3(144, 4, 2), dim3(256), 0, stream,
                       x, wt, b1, a1, b2, a2, ba, aa, qb, kb, vtb);
    hipLaunchKernelGGL(attn_kernel, dim3(NQT, nch, 2), dim3(256), 0, stream,
                       qb, kb, vtb, o_part, ml, nch, chunk_j);
    hipLaunchKernelGGL(combine_kernel, dim3(2 * NQT * 128 * 64 / 256), dim3(256), 0, stream,
                       o_part, ml, out, nch);
}